// Round 10
// baseline (6751.646 us; speedup 1.0000x reference)
//
#include <hip/hip_runtime.h>

// ---------------------------------------------------------------------------
// SimpleGPT forward on MI355X. Round 18: R11 base (best, 5584us), ONE change:
// chunkB capped at 256. Traffic audit: total HBM-path traffic ~17.4 GB at
// chunkB=512 / 5.58ms = 3.1 TB/s -> runtime == traffic / stream-rate. At
// chunkB=512 the live intermediate set (x,h,qkv,ab,fb) = ~259 MB, JUST over
// the 256MB Infinity Cache -> write-then-read streams (fb 94MB w+r, qkv 71MB
// w+r) thrash L3 and every gemm runs ~1.8 TB/s latency-limited. chunkB=256
// -> working set ~151 MB, L3-resident. Kernels byte-identical to R11.
// ---------------------------------------------------------------------------

#define B_  2048
#define T_  60
#define C_  384
#define H_  6
#define HS_ 64
#define L_  6
#define FF_ 1536
#define V_  65

typedef unsigned int  u32;
typedef unsigned short u16;
typedef short bf16x8 __attribute__((ext_vector_type(8)));
typedef float f32x4  __attribute__((ext_vector_type(4)));

__device__ __forceinline__ float bf2f(u32 u) {
  return __uint_as_float(u << 16);
}
__device__ __forceinline__ u16 f2bf(float f) {
  u32 u = __float_as_uint(f);
  u = u + 0x7FFFu + ((u >> 16) & 1u);   // RNE; inputs are finite
  return (u16)(u >> 16);
}

typedef const __attribute__((address_space(1))) unsigned int gas_u32;
typedef __attribute__((address_space(3))) unsigned int las_u32;
__device__ __forceinline__ void gload16(const u16* g, u16* l) {
  __builtin_amdgcn_global_load_lds((gas_u32*)g, (las_u32*)l, 16, 0, 0);
}

// ------------------------------------------------ weight transpose+convert
__global__ void tconv_k(const float* __restrict__ src, u16* __restrict__ dst,
                        int K, int N, long srcStride, int nH, long sL, long sH)
{
  __shared__ float t[32][33];
  int z = blockIdx.z;
  int l = z / nH, hh = z % nH;
  const float* s = src + (long)z * srcStride;
  u16* d = dst + l * sL + hh * sH;
  int n0 = blockIdx.x * 32, k0 = blockIdx.y * 32;
  for (int yy = threadIdx.y; yy < 32; yy += 8) {
    int k = k0 + yy, n = n0 + threadIdx.x;
    t[yy][threadIdx.x] = (k < K && n < N) ? s[(long)k * N + n] : 0.f;
  }
  __syncthreads();
  for (int yy = threadIdx.y; yy < 32; yy += 8) {
    int n = n0 + yy, k = k0 + threadIdx.x;
    if (n < N && k < K) d[(long)n * K + k] = f2bf(t[threadIdx.x][yy]);
  }
}

// ---------------------------------------------------------------- embedding
__global__ __launch_bounds__(256) void embed_k(const int* __restrict__ ctx,
    const float* __restrict__ tok, const float* __restrict__ pos,
    float* __restrict__ x)
{
  int idx = blockIdx.x * 256 + threadIdx.x;
  int row = idx / (C_ / 4);
  int c   = (idx % (C_ / 4)) * 4;
  int t   = row % T_;
  int tk  = ctx[row];
  float4 a = *(const float4*)(tok + (long)tk * C_ + c);
  float4 p = *(const float4*)(pos + (long)t  * C_ + c);
  float4 o = make_float4(a.x + p.x, a.y + p.y, a.z + p.z, a.w + p.w);
  *(float4*)(x + (long)idx * 4) = o;
}

// ---------------------------------------------------------------- layernorm
__global__ __launch_bounds__(256) void ln_k(const float* __restrict__ x,
    const float* __restrict__ g, const float* __restrict__ b,
    u16* __restrict__ h)
{
  int lane = threadIdx.x & 63;
  int wv   = threadIdx.x >> 6;
  long row = (long)blockIdx.x * 4 + wv;
  const float* xr = x + row * C_;
  int c0 = lane * 6;
  float v0[6];
  #pragma unroll
  for (int i = 0; i < 6; i++) v0[i] = xr[c0 + i];
  float s = 0.f, sq = 0.f;
  #pragma unroll
  for (int i = 0; i < 6; i++) { s += v0[i]; sq += v0[i] * v0[i]; }
  #pragma unroll
  for (int off = 32; off > 0; off >>= 1) {
    s  += __shfl_xor(s,  off, 64);
    sq += __shfl_xor(sq, off, 64);
  }
  float mu  = s * (1.f / C_);
  float var = sq * (1.f / C_) - mu * mu;
  float rs  = rsqrtf(var + 1e-5f);
  u16* hr = h + row * C_;
  #pragma unroll
  for (int i = 0; i < 6; i++) {
    float hv = (v0[i] - mu) * rs * g[c0 + i] + b[c0 + i];
    hr[c0 + i] = f2bf(hv);
  }
}

// ------------------------------------------------------------- MFMA GEMM 128
// out[M,N] = act(A[M,K](bf16) @ Wt^T + bias) [+ resid]; Wt bf16 [N][K].
// M%128==0, N%128==0, K%32==0. 1-D grid mT*nT, XCD swizzle when mT%8==0.
// 512 threads (8 waves, 4x2 grid, 32x64/wave). global_load_lds staging into
// double-buffered LDS; swizzle applied on the per-lane global source:
// LDS chunk c (=tid) holds A[row=c>>2][seg = (c&3)^((row>>2)&3)]; reads use
// swR = l4^(l15>>2). One __syncthreads per k-iter (vmcnt+lgkm drain).
template<int RELU, int RES, int OBF>
__global__ __launch_bounds__(512) void gemm128g(const u16* __restrict__ A,
    const u16* __restrict__ Wt, const float* __restrict__ bias,
    const float* __restrict__ resid, void* __restrict__ outp,
    int N, int K, int mT, int nT)
{
  __shared__ __align__(16) u16 As[2][128][4][8];   // 16 KB
  __shared__ __align__(16) u16 Bs[2][128][4][8];   // 16 KB
  int tid = threadIdx.x;
  int bid = blockIdx.x;
  int mtile, ntile;
  if ((mT & 7) == 0) {
    int xcd = bid & 7, loc = bid >> 3;
    int q = loc / nT;
    mtile = xcd * (mT >> 3) + q;
    ntile = loc - q * nT;
  } else {
    int q = bid / nT;
    mtile = q;
    ntile = bid - q * nT;
  }
  long mBase = (long)mtile * 128;
  int  nBase = ntile * 128;
  int lane = tid & 63, wv = tid >> 6;
  int l15 = lane & 15, l4 = lane >> 4;
  int wr = wv >> 1, wc = wv & 1;          // 4x2 wave grid, 32x64 per wave
  // staging: chunk c = tid; row = c>>2, sIdx = c&3, seg = sIdx^((row>>2)&3)
  int srow = tid >> 2;
  int seg  = (tid & 3) ^ ((tid >> 4) & 3);
  const u16* aL = A  + (mBase + srow) * (long)K + seg * 8;
  const u16* bL = Wt + ((long)nBase + srow) * K + seg * 8;
  u16* aD0 = &As[0][wv << 4][0][0];       // wave-uniform LDS dests
  u16* bD0 = &Bs[0][wv << 4][0][0];
  u16* aD1 = &As[1][wv << 4][0][0];
  u16* bD1 = &Bs[1][wv << 4][0][0];
  int swR = l4 ^ (l15 >> 2);

  f32x4 acc[2][4];
  #pragma unroll
  for (int i = 0; i < 2; i++)
    #pragma unroll
    for (int j = 0; j < 4; j++)
      acc[i][j] = (f32x4){0.f, 0.f, 0.f, 0.f};

  // prologue: stage k=0 into buf0
  gload16(aL, aD0);
  gload16(bL, bD0);
  __syncthreads();

  int cur = 0;
  for (int k0 = 0; k0 < K; k0 += 32) {
    if (k0 + 32 < K) {                    // issue next-tile DMA first
      gload16(aL + k0 + 32, cur ? aD0 : aD1);
      gload16(bL + k0 + 32, cur ? bD0 : bD1);
    }
    bf16x8 af[2], bfr[4];
    #pragma unroll
    for (int i = 0; i < 2; i++)
      af[i] = *(const bf16x8*)&As[cur][wr * 32 + i * 16 + l15][swR][0];
    #pragma unroll
    for (int j = 0; j < 4; j++)
      bfr[j] = *(const bf16x8*)&Bs[cur][wc * 64 + j * 16 + l15][swR][0];
    #pragma unroll
    for (int i = 0; i < 2; i++)
      #pragma unroll
      for (int j = 0; j < 4; j++)
        acc[i][j] = __builtin_amdgcn_mfma_f32_16x16x32_bf16(
            af[i], bfr[j], acc[i][j], 0, 0, 0);
    __syncthreads();                      // drains vmcnt (DMA) + lgkm
    cur ^= 1;
  }

  #pragma unroll
  for (int i = 0; i < 2; i++) {
    #pragma unroll
    for (int j = 0; j < 4; j++) {
      int n = nBase + wc * 64 + j * 16 + l15;
      float bv = bias ? bias[n] : 0.f;
      #pragma unroll
      for (int r = 0; r < 4; r++) {
        long row = mBase + wr * 32 + i * 16 + l4 * 4 + r;
        float vv = acc[i][j][r] + bv;
        if (RELU) vv = fmaxf(vv, 0.f);
        if (RES)  vv += resid[row * N + n];
        if (OBF) ((u16*)outp)[row * N + n] = f2bf(vv);
        else     ((float*)outp)[row * N + n] = vv;
      }
    }
  }
}

// ------------------------------------------------------------- head GEMM
template<int OBF>
__global__ __launch_bounds__(256) void gemm_head(const u16* __restrict__ A,
    const u16* __restrict__ Wt, const float* __restrict__ bias,
    void* __restrict__ outp, int N, int K)
{
  __shared__ __align__(16) u16 As[128][4][8];
  __shared__ __align__(16) u16 Bs[64][4][8];
  int tid  = threadIdx.x;
  int nt   = blockIdx.x;
  int nBase = nt * 64;
  long mBase = (long)blockIdx.y * 128;
  int lane = tid & 63, wv = tid >> 6;
  int l15 = lane & 15, l4 = lane >> 4;
  int sseg = tid & 3;
  int srow = tid >> 2;
  int swW = sseg ^ ((srow >> 2) & 3);
  int swR = l4 ^ (l15 >> 2);
  const u16* a0p = A + (mBase + srow) * K + sseg * 8;
  const u16* a1p = a0p + (long)64 * K;
  bool colOK = (nBase + srow) < N;
  const u16* bp  = Wt + (long)(nBase + srow) * K + sseg * 8;

  f32x4 acc[2][4];
  #pragma unroll
  for (int i = 0; i < 2; i++)
    #pragma unroll
    for (int j = 0; j < 4; j++)
      acc[i][j] = (f32x4){0.f, 0.f, 0.f, 0.f};

  for (int k0 = 0; k0 < K; k0 += 32) {
    uint4 av0 = *(const uint4*)(a0p + k0);
    uint4 av1 = *(const uint4*)(a1p + k0);
    uint4 bv  = colOK ? *(const uint4*)(bp + k0) : make_uint4(0, 0, 0, 0);
    *(uint4*)&As[srow][swW][0]      = av0;
    *(uint4*)&As[srow + 64][swW][0] = av1;
    *(uint4*)&Bs[srow][swW][0]      = bv;
    __syncthreads();
    bf16x8 af[2], bfr[4];
    af[0] = *(const bf16x8*)&As[wv * 32 + l15][swR][0];
    af[1] = *(const bf16x8*)&As[wv * 32 + 16 + l15][swR][0];
    #pragma unroll
    for (int j = 0; j < 4; j++)
      bfr[j] = *(const bf16x8*)&Bs[j * 16 + l15][swR][0];
    #pragma unroll
    for (int i = 0; i < 2; i++)
      #pragma unroll
      for (int j = 0; j < 4; j++)
        acc[i][j] = __builtin_amdgcn_mfma_f32_16x16x32_bf16(
            af[i], bfr[j], acc[i][j], 0, 0, 0);
    __syncthreads();
  }

  #pragma unroll
  for (int i = 0; i < 2; i++) {
    #pragma unroll
    for (int j = 0; j < 4; j++) {
      int n = nBase + j * 16 + l15;
      if (n < N) {
        #pragma unroll
        for (int r = 0; r < 4; r++) {
          long row = mBase + wv * 32 + i * 16 + l4 * 4 + r;
          float vv = acc[i][j][r];
          if (bias) vv += bias[n];
          if (OBF) ((u16*)outp)[row * N + n] = f2bf(vv);
          else     ((float*)outp)[row * N + n] = vv;
        }
      }
    }
  }
}

// ---------------------------------------------------------------- attention
// MFMA flash-style: one block per (b, head); qkv [BTc][1152]; ao [BTc][384].
__global__ __launch_bounds__(256) void attn_k(const u16* __restrict__ qkv,
    u16* __restrict__ ao)
{
  __shared__ __align__(16) u16 qs[64][72];
  __shared__ __align__(16) u16 ks[64][72];
  __shared__ __align__(16) u16 vT[64][72];
  __shared__ __align__(16) u16 ps[64][72];
  int tid = threadIdx.x;
  int bb = blockIdx.x / H_;
  int hh = blockIdx.x % H_;
  const u16* base = qkv + ((long)bb * T_) * 1152 + hh * HS_;

  for (int i = tid; i < 576; i += 256)
    ((uint4*)vT)[i] = make_uint4(0, 0, 0, 0);
  __syncthreads();

  for (int i = tid; i < 480; i += 256) {
    int t = i >> 3, d0 = (i & 7) << 3;
    const u16* rp = base + (long)t * 1152;
    *(uint4*)&qs[t][d0] = *(const uint4*)(rp + d0);
    *(uint4*)&ks[t][d0] = *(const uint4*)(rp + 384 + d0);
    uint4 rv = *(const uint4*)(rp + 768 + d0);
    u16 vv[8] = {(u16)(rv.x & 0xffffu), (u16)(rv.x >> 16),
                 (u16)(rv.y & 0xffffu), (u16)(rv.y >> 16),
                 (u16)(rv.z & 0xffffu), (u16)(rv.z >> 16),
                 (u16)(rv.w & 0xffffu), (u16)(rv.w >> 16)};
    #pragma unroll
    for (int m = 0; m < 8; m++) vT[d0 + m][t] = vv[m];
  }
  __syncthreads();

  int lane = tid & 63, wv = tid >> 6;
  int l15 = lane & 15, quad = lane >> 4;

  bf16x8 aq0 = *(const bf16x8*)&qs[wv * 16 + l15][quad * 8];
  bf16x8 aq1 = *(const bf16x8*)&qs[wv * 16 + l15][32 + quad * 8];
  f32x4 s[4];
  #pragma unroll
  for (int jt = 0; jt < 4; jt++) {
    bf16x8 b0 = *(const bf16x8*)&ks[jt * 16 + l15][quad * 8];
    bf16x8 b1 = *(const bf16x8*)&ks[jt * 16 + l15][32 + quad * 8];
    f32x4 a2 = (f32x4){0.f, 0.f, 0.f, 0.f};
    a2 = __builtin_amdgcn_mfma_f32_16x16x32_bf16(aq0, b0, a2, 0, 0, 0);
    a2 = __builtin_amdgcn_mfma_f32_16x16x32_bf16(aq1, b1, a2, 0, 0, 0);
    s[jt] = a2;
  }

  int rbase = wv * 16 + quad * 4;
  #pragma unroll
  for (int r = 0; r < 4; r++) {
    int row = rbase + r;
    float v0[4];
    #pragma unroll
    for (int jt = 0; jt < 4; jt++) {
      int col = jt * 16 + l15;
      float sv = s[jt][r] * 0.125f;
      v0[jt] = (col <= row) ? sv : -1e30f;
    }
    float m = fmaxf(fmaxf(v0[0], v0[1]), fmaxf(v0[2], v0[3]));
    #pragma unroll
    for (int off = 1; off < 16; off <<= 1) m = fmaxf(m, __shfl_xor(m, off, 64));
    float sum = 0.f;
    #pragma unroll
    for (int jt = 0; jt < 4; jt++) { v0[jt] = __expf(v0[jt] - m); sum += v0[jt]; }
    #pragma unroll
    for (int off = 1; off < 16; off <<= 1) sum += __shfl_xor(sum, off, 64);
    float inv = 1.f / sum;
    #pragma unroll
    for (int jt = 0; jt < 4; jt++)
      ps[row][jt * 16 + l15] = f2bf(v0[jt] * inv);
  }
  __syncthreads();

  bf16x8 ap0 = *(const bf16x8*)&ps[wv * 16 + l15][quad * 8];
  bf16x8 ap1 = *(const bf16x8*)&ps[wv * 16 + l15][32 + quad * 8];
  long obase = ((long)bb * T_) * C_ + hh * HS_;
  #pragma unroll
  for (int dt = 0; dt < 4; dt++) {
    bf16x8 b0 = *(const bf16x8*)&vT[dt * 16 + l15][quad * 8];
    bf16x8 b1 = *(const bf16x8*)&vT[dt * 16 + l15][32 + quad * 8];
    f32x4 a2 = (f32x4){0.f, 0.f, 0.f, 0.f};
    a2 = __builtin_amdgcn_mfma_f32_16x16x32_bf16(ap0, b0, a2, 0, 0, 0);
    a2 = __builtin_amdgcn_mfma_f32_16x16x32_bf16(ap1, b1, a2, 0, 0, 0);
    #pragma unroll
    for (int r = 0; r < 4; r++) {
      int row = rbase + r;
      if (row < T_)
        ao[obase + (long)row * C_ + dt * 16 + l15] = f2bf(a2[r]);
    }
  }
}

// ---------------------------------------------------------------- launch
extern "C" void kernel_launch(void* const* d_in, const int* in_sizes, int n_in,
                              void* d_out, int out_size, void* d_ws, size_t ws_size,
                              hipStream_t stream)
{
  const int*   ctx  = (const int*)  d_in[0];
  const float* tok  = (const float*)d_in[1];
  const float* pos  = (const float*)d_in[2];
  const float* wq   = (const float*)d_in[3];
  const float* wk   = (const float*)d_in[4];
  const float* wv   = (const float*)d_in[5];
  const float* wo   = (const float*)d_in[6];
  const float* bo   = (const float*)d_in[7];
  const float* ln1g = (const float*)d_in[8];
  const float* ln1b = (const float*)d_in[9];
  const float* ln2g = (const float*)d_in[10];
  const float* ln2b = (const float*)d_in[11];
  const float* w1   = (const float*)d_in[12];
  const float* b1   = (const float*)d_in[13];
  const float* w2   = (const float*)d_in[14];
  const float* b2   = (const float*)d_in[15];
  const float* lnfg = (const float*)d_in[16];
  const float* lnfb = (const float*)d_in[17];
  const float* lmw  = (const float*)d_in[18];
  const float* lmb  = (const float*)d_in[19];
  float* out = (float*)d_out;

  const long nQKV = (long)L_ * H_ * C_ * HS_;
  const long nWO  = (long)L_ * C_ * C_;
  const long nW1  = (long)L_ * C_ * FF_;
  const long nLM  = (long)C_ * V_;
  u16* wqkvT = (u16*)d_ws;                       // [L][1152][384]
  u16* woT = wqkvT + 3 * nQKV;
  u16* w1T = woT + nWO;
  u16* w2T = w1T + nW1;
  u16* lmT = w2T + nW1;
  const size_t wbytes = (size_t)(nQKV * 3 + nWO + nW1 * 2 + nLM) * 2;

  // chunkB capped at 256: live intermediates (x,h,qkv,ab,fb ~151MB incl
  // weights) stay Infinity-Cache-resident; 512 was ~259MB (thrash margin).
  int chunkB = 32;
  {
    const int cand[] = {256, 128, 64, 32};
    for (int i = 0; i < 4; i++) {
      size_t U = (size_t)cand[i] * T_ * C_ * 2;
      if (wbytes + 7 * U <= ws_size) { chunkB = cand[i]; break; }
    }
  }
  const long BTc = (long)chunkB * T_;
  char* wsb = (char*)d_ws + wbytes;
  const size_t U = (size_t)BTc * C_ * 2;
  float* x    = (float*)wsb;             // 2U
  u16*   h    = (u16*)(wsb + 2 * U);     // 1U
  char*  reg  = wsb + 3 * U;             // 4U: qkv(3U) + ab(1U); fb aliases
  u16* qkvb = (u16*)reg;
  u16* ab   = (u16*)(reg + 3 * U);
  u16* fb   = (u16*)reg;                 // alias: qkv/ab dead before MLP

  {
    dim3 tb(32, 8);
    const long sL = 1152L * 384, sH = 64L * 384, sec = 384L * 384;
    tconv_k<<<dim3(2, 12, L_ * H_), tb, 0, stream>>>(wq, wqkvT,
        C_, HS_, (long)C_ * HS_, H_, sL, sH);
    tconv_k<<<dim3(2, 12, L_ * H_), tb, 0, stream>>>(wk, wqkvT + sec,
        C_, HS_, (long)C_ * HS_, H_, sL, sH);
    tconv_k<<<dim3(2, 12, L_ * H_), tb, 0, stream>>>(wv, wqkvT + 2 * sec,
        C_, HS_, (long)C_ * HS_, H_, sL, sH);
    tconv_k<<<dim3(12, 12, L_), tb, 0, stream>>>(wo, woT,
        C_, C_, (long)C_ * C_, 1, (long)C_ * C_, 0);
    tconv_k<<<dim3(48, 12, L_), tb, 0, stream>>>(w1, w1T,
        C_, FF_, (long)C_ * FF_, 1, (long)C_ * FF_, 0);
    tconv_k<<<dim3(12, 48, L_), tb, 0, stream>>>(w2, w2T,
        FF_, C_, (long)FF_ * C_, 1, (long)FF_ * C_, 0);
    tconv_k<<<dim3(3, 12, 1), tb, 0, stream>>>(lmw, lmT,
        C_, V_, (long)C_ * V_, 1, 0, 0);
  }

  const long qkvL = 1152L * 384;
  const long woL  = (long)C_ * C_;
  const long w1L  = (long)C_ * FF_;
  dim3 blk(256);
  dim3 blk5(512);
  dim3 gEmb((u32)(BTc * C_ / 4 / 256));
  dim3 gLN((u32)(BTc / 4));
  int mT = (int)(BTc / 128);
  dim3 gHd(2, (u32)(BTc / 128));
  dim3 gAt((u32)(chunkB * H_));

  for (int c0 = 0; c0 < B_; c0 += chunkB) {
    const long tok0 = (long)c0 * T_;
    const int* ctxc = ctx + tok0;
    float* outc = out + tok0 * V_;

    embed_k<<<gEmb, blk, 0, stream>>>(ctxc, tok, pos, x);

    for (int l = 0; l < L_; l++) {
      ln_k<<<gLN, blk, 0, stream>>>(x, ln1g + l * C_, ln1b + l * C_, h);
      gemm128g<0,0,1><<<dim3(mT * 9), blk5, 0, stream>>>(h, wqkvT + l * qkvL,
          nullptr, nullptr, qkvb, 1152, C_, mT, 9);
      attn_k<<<gAt, blk, 0, stream>>>(qkvb, ab);
      gemm128g<0,1,0><<<dim3(mT * 3), blk5, 0, stream>>>(ab, woT + l * woL,
          bo + l * C_, x, x, C_, C_, mT, 3);
      ln_k<<<gLN, blk, 0, stream>>>(x, ln2g + l * C_, ln2b + l * C_, h);
      gemm128g<1,0,1><<<dim3(mT * 12), blk5, 0, stream>>>(h, w1T + l * w1L,
          b1 + l * FF_, nullptr, fb, FF_, C_, mT, 12);
      gemm128g<0,1,0><<<dim3(mT * 3), blk5, 0, stream>>>(fb, w2T + l * w1L,
          b2 + l * C_, x, x, C_, FF_, mT, 3);
    }

    ln_k<<<gLN, blk, 0, stream>>>(x, lnfg, lnfb, h);
    gemm_head<0><<<gHd, blk, 0, stream>>>(h, lmT, lmb, outc, V_, C_);
  }
}

// Round 11
// 5892.534 us; speedup vs baseline: 1.1458x; 1.1458x over previous
//
#include <hip/hip_runtime.h>

// ---------------------------------------------------------------------------
// SimpleGPT forward on MI355X. Round 19: R11 base (best, 5584us) + FUSED MLP.
// R9-R17: eight GEMM-structure variants all ~500 TF -> not loop-bound.
// R18: chunkB 256 regressed 1.17ms -> dispatch bubbles ~7.5us each; traffic +
// dispatch count are the binding constraints. Biggest item: fb intermediate
// (94MB w + 94MB r per chunk-layer = 28% of traffic) + 1 dispatch boundary.
// mlp_fused: per 128-row block, for cc in 0..11:
//   U: u_cc[128x128] = relu(h[128x384] @ W1[:,cc*128..] + b1)  (R11 loop)
//      -> LDS, swizzle seg' = (col>>3) ^ (row&15)  (bijective, 2-way banks)
//   D: acc_out[128x384] += u_cc @ W2[cc*128..,:]   (K=128, 4 k-iters)
// acc_out held in regs across cc; epilogue += b2 + resid -> x (f32).
// fb deleted; h aliases dead ab slot (6U workspace). Others = R11 verbatim.
// ---------------------------------------------------------------------------

#define B_  2048
#define T_  60
#define C_  384
#define H_  6
#define HS_ 64
#define L_  6
#define FF_ 1536
#define V_  65

typedef unsigned int  u32;
typedef unsigned short u16;
typedef short bf16x8 __attribute__((ext_vector_type(8)));
typedef float f32x4  __attribute__((ext_vector_type(4)));

__device__ __forceinline__ float bf2f(u32 u) {
  return __uint_as_float(u << 16);
}
__device__ __forceinline__ u16 f2bf(float f) {
  u32 u = __float_as_uint(f);
  u = u + 0x7FFFu + ((u >> 16) & 1u);   // RNE; inputs are finite
  return (u16)(u >> 16);
}

typedef const __attribute__((address_space(1))) unsigned int gas_u32;
typedef __attribute__((address_space(3))) unsigned int las_u32;
__device__ __forceinline__ void gload16(const u16* g, u16* l) {
  __builtin_amdgcn_global_load_lds((gas_u32*)g, (las_u32*)l, 16, 0, 0);
}
#define MFMA16(a, b, c) __builtin_amdgcn_mfma_f32_16x16x32_bf16((a), (b), (c), 0, 0, 0)

// ------------------------------------------------ weight transpose+convert
__global__ void tconv_k(const float* __restrict__ src, u16* __restrict__ dst,
                        int K, int N, long srcStride, int nH, long sL, long sH)
{
  __shared__ float t[32][33];
  int z = blockIdx.z;
  int l = z / nH, hh = z % nH;
  const float* s = src + (long)z * srcStride;
  u16* d = dst + l * sL + hh * sH;
  int n0 = blockIdx.x * 32, k0 = blockIdx.y * 32;
  for (int yy = threadIdx.y; yy < 32; yy += 8) {
    int k = k0 + yy, n = n0 + threadIdx.x;
    t[yy][threadIdx.x] = (k < K && n < N) ? s[(long)k * N + n] : 0.f;
  }
  __syncthreads();
  for (int yy = threadIdx.y; yy < 32; yy += 8) {
    int n = n0 + yy, k = k0 + threadIdx.x;
    if (n < N && k < K) d[(long)n * K + k] = f2bf(t[threadIdx.x][yy]);
  }
}

// ---------------------------------------------------------------- embedding
__global__ __launch_bounds__(256) void embed_k(const int* __restrict__ ctx,
    const float* __restrict__ tok, const float* __restrict__ pos,
    float* __restrict__ x)
{
  int idx = blockIdx.x * 256 + threadIdx.x;
  int row = idx / (C_ / 4);
  int c   = (idx % (C_ / 4)) * 4;
  int t   = row % T_;
  int tk  = ctx[row];
  float4 a = *(const float4*)(tok + (long)tk * C_ + c);
  float4 p = *(const float4*)(pos + (long)t  * C_ + c);
  float4 o = make_float4(a.x + p.x, a.y + p.y, a.z + p.z, a.w + p.w);
  *(float4*)(x + (long)idx * 4) = o;
}

// ---------------------------------------------------------------- layernorm
__global__ __launch_bounds__(256) void ln_k(const float* __restrict__ x,
    const float* __restrict__ g, const float* __restrict__ b,
    u16* __restrict__ h)
{
  int lane = threadIdx.x & 63;
  int wv   = threadIdx.x >> 6;
  long row = (long)blockIdx.x * 4 + wv;
  const float* xr = x + row * C_;
  int c0 = lane * 6;
  float v0[6];
  #pragma unroll
  for (int i = 0; i < 6; i++) v0[i] = xr[c0 + i];
  float s = 0.f, sq = 0.f;
  #pragma unroll
  for (int i = 0; i < 6; i++) { s += v0[i]; sq += v0[i] * v0[i]; }
  #pragma unroll
  for (int off = 32; off > 0; off >>= 1) {
    s  += __shfl_xor(s,  off, 64);
    sq += __shfl_xor(sq, off, 64);
  }
  float mu  = s * (1.f / C_);
  float var = sq * (1.f / C_) - mu * mu;
  float rs  = rsqrtf(var + 1e-5f);
  u16* hr = h + row * C_;
  #pragma unroll
  for (int i = 0; i < 6; i++) {
    float hv = (v0[i] - mu) * rs * g[c0 + i] + b[c0 + i];
    hr[c0 + i] = f2bf(hv);
  }
}

// ------------------------------------------------------------- MFMA GEMM 128
// out[M,N] = act(A[M,K](bf16) @ Wt^T + bias) [+ resid]; Wt bf16 [N][K].
// R11 verbatim. 512 threads (8 waves, 4x2 grid, 32x64/wave). gload_lds
// double-buffered staging; source-side swizzle; reads swR = l4^(l15>>2).
template<int RELU, int RES, int OBF>
__global__ __launch_bounds__(512) void gemm128g(const u16* __restrict__ A,
    const u16* __restrict__ Wt, const float* __restrict__ bias,
    const float* __restrict__ resid, void* __restrict__ outp,
    int N, int K, int mT, int nT)
{
  __shared__ __align__(16) u16 As[2][128][4][8];   // 16 KB
  __shared__ __align__(16) u16 Bs[2][128][4][8];   // 16 KB
  int tid = threadIdx.x;
  int bid = blockIdx.x;
  int mtile, ntile;
  if ((mT & 7) == 0) {
    int xcd = bid & 7, loc = bid >> 3;
    int q = loc / nT;
    mtile = xcd * (mT >> 3) + q;
    ntile = loc - q * nT;
  } else {
    int q = bid / nT;
    mtile = q;
    ntile = bid - q * nT;
  }
  long mBase = (long)mtile * 128;
  int  nBase = ntile * 128;
  int lane = tid & 63, wv = tid >> 6;
  int l15 = lane & 15, l4 = lane >> 4;
  int wr = wv >> 1, wc = wv & 1;          // 4x2 wave grid, 32x64 per wave
  int srow = tid >> 2;
  int seg  = (tid & 3) ^ ((tid >> 4) & 3);
  const u16* aL = A  + (mBase + srow) * (long)K + seg * 8;
  const u16* bL = Wt + ((long)nBase + srow) * K + seg * 8;
  u16* aD0 = &As[0][wv << 4][0][0];       // wave-uniform LDS dests
  u16* bD0 = &Bs[0][wv << 4][0][0];
  u16* aD1 = &As[1][wv << 4][0][0];
  u16* bD1 = &Bs[1][wv << 4][0][0];
  int swR = l4 ^ (l15 >> 2);

  f32x4 acc[2][4];
  #pragma unroll
  for (int i = 0; i < 2; i++)
    #pragma unroll
    for (int j = 0; j < 4; j++)
      acc[i][j] = (f32x4){0.f, 0.f, 0.f, 0.f};

  gload16(aL, aD0);
  gload16(bL, bD0);
  __syncthreads();

  int cur = 0;
  for (int k0 = 0; k0 < K; k0 += 32) {
    if (k0 + 32 < K) {
      gload16(aL + k0 + 32, cur ? aD0 : aD1);
      gload16(bL + k0 + 32, cur ? bD0 : bD1);
    }
    bf16x8 af[2], bfr[4];
    #pragma unroll
    for (int i = 0; i < 2; i++)
      af[i] = *(const bf16x8*)&As[cur][wr * 32 + i * 16 + l15][swR][0];
    #pragma unroll
    for (int j = 0; j < 4; j++)
      bfr[j] = *(const bf16x8*)&Bs[cur][wc * 64 + j * 16 + l15][swR][0];
    #pragma unroll
    for (int i = 0; i < 2; i++)
      #pragma unroll
      for (int j = 0; j < 4; j++)
        acc[i][j] = __builtin_amdgcn_mfma_f32_16x16x32_bf16(
            af[i], bfr[j], acc[i][j], 0, 0, 0);
    __syncthreads();
    cur ^= 1;
  }

  #pragma unroll
  for (int i = 0; i < 2; i++) {
    #pragma unroll
    for (int j = 0; j < 4; j++) {
      int n = nBase + wc * 64 + j * 16 + l15;
      float bv = bias ? bias[n] : 0.f;
      #pragma unroll
      for (int r = 0; r < 4; r++) {
        long row = mBase + wr * 32 + i * 16 + l4 * 4 + r;
        float vv = acc[i][j][r] + bv;
        if (RELU) vv = fmaxf(vv, 0.f);
        if (RES)  vv += resid[row * N + n];
        if (OBF) ((u16*)outp)[row * N + n] = f2bf(vv);
        else     ((float*)outp)[row * N + n] = vv;
      }
    }
  }
}

// ---------------------------------------------------------------- fused MLP
// x += relu(h @ W1 + b1) @ W2 + b2. h [M][384] bf16; W1t [1536][384] bf16;
// W2t [384][1536] bf16. 512 threads, 8 waves. Block tile 128 rows x 384 cols.
// Per cc (12 chunks of 128 fb-cols): phase U computes u_cc (R11 2-buf loop,
// wave grid 4x2, 32x64), writes u to LDS [row][seg16^(row&15)][8]; phase D
// accumulates out += u_cc @ W2slice (wave grid 2x4, 64x96, K=128).
__global__ __launch_bounds__(512) void mlp_fused(const u16* __restrict__ h,
    const u16* __restrict__ W1t, const float* __restrict__ b1,
    const u16* __restrict__ W2t, const float* __restrict__ b2,
    float* __restrict__ x, int mT)
{
  // LDS (u16 units): u [0,16384) ; UA 16384+cur*4096 ; UB 32768+cur*4096 ;
  // DB 49152+cur*12288 (384x32 swizzled). Total 73728 u16 = 144 KB.
  __shared__ __align__(16) u16 lds[73728];
  int tid = threadIdx.x;
  int bid = blockIdx.x;
  int mtile;
  if ((mT & 7) == 0) {
    int xcd = bid & 7, loc = bid >> 3;
    mtile = xcd * (mT >> 3) + loc;
  } else {
    mtile = bid;
  }
  long mBase = (long)mtile * 128;
  int lane = tid & 63, w = tid >> 6;
  int l15 = lane & 15, l4 = lane >> 4;
  int wrU = w >> 1, wcU = w & 1;          // U: 4x2, 32x64 per wave
  int wr2 = w >> 2, wc2 = w & 3;          // D: 2x4, 64x96 per wave
  int srow = tid >> 2;                    // 0..127
  int seg  = (tid & 3) ^ ((tid >> 4) & 3);
  const u16* aL = h   + (mBase + srow) * 384 + seg * 8;
  const u16* bU = W1t + (long)srow * 384 + seg * 8;
  const u16* bD = W2t + (long)srow * 1536 + seg * 8;
  int wvOff = w << 9;                     // wave-uniform stage base (u16)
  int swR = l4 ^ (l15 >> 2);
  int uaOff = (wrU * 32 + l15) * 32 + swR * 8;
  int ubOff = (wcU * 64 + l15) * 32 + swR * 8;
  int dbOff = (wc2 * 96 + l15) * 32 + swR * 8;

  f32x4 accO[4][6];
  #pragma unroll
  for (int i = 0; i < 4; i++)
    #pragma unroll
    for (int j = 0; j < 6; j++)
      accO[i][j] = (f32x4){0.f, 0.f, 0.f, 0.f};

  for (int cc = 0; cc < 12; ++cc) {
    const u16* bUc = bU + cc * 49152;     // W1t rows cc*128..
    // ---- phase U: u_cc = relu(h_tile @ W1slice + b1) ----
    gload16(aL,  &lds[16384 + wvOff]);
    gload16(bUc, &lds[32768 + wvOff]);
    __syncthreads();
    f32x4 accU[2][4];
    #pragma unroll
    for (int i = 0; i < 2; i++)
      #pragma unroll
      for (int j = 0; j < 4; j++)
        accU[i][j] = (f32x4){0.f, 0.f, 0.f, 0.f};
    int cur = 0;
    for (int kt = 0; kt < 12; ++kt) {
      int k0 = kt * 32;
      if (kt < 11) {
        gload16(aL  + k0 + 32, &lds[16384 + ((cur ^ 1) << 12) + wvOff]);
        gload16(bUc + k0 + 32, &lds[32768 + ((cur ^ 1) << 12) + wvOff]);
      }
      bf16x8 af[2], bf[4];
      #pragma unroll
      for (int i = 0; i < 2; i++)
        af[i] = *(const bf16x8*)&lds[16384 + (cur << 12) + uaOff + i * 512];
      #pragma unroll
      for (int j = 0; j < 4; j++)
        bf[j] = *(const bf16x8*)&lds[32768 + (cur << 12) + ubOff + j * 512];
      #pragma unroll
      for (int i = 0; i < 2; i++)
        #pragma unroll
        for (int j = 0; j < 4; j++)
          accU[i][j] = MFMA16(af[i], bf[j], accU[i][j]);
      __syncthreads();
      cur ^= 1;
    }
    // write u (+b1, relu) into LDS: elem = row*128 + ((col>>3)^(row&15))*8
    //   + (col&7); row&15 = l4*4+r here.
    #pragma unroll
    for (int j = 0; j < 4; ++j) {
      int col = wcU * 64 + j * 16 + l15;
      float bv = b1[cc * 128 + col];
      int chi = col >> 3, cpos = col & 7;
      #pragma unroll
      for (int i = 0; i < 2; ++i)
        #pragma unroll
        for (int r = 0; r < 4; ++r) {
          int row = wrU * 32 + i * 16 + l4 * 4 + r;
          float vv = fmaxf(accU[i][j][r] + bv, 0.f);
          lds[row * 128 + ((chi ^ (l4 * 4 + r)) << 3) + cpos] = f2bf(vv);
        }
    }
    // stage D kk=0 (W2t rows srow/srow+128/srow+256, k = cc*128..+32)
    const u16* bDc = bD + cc * 128;
    gload16(bDc,          &lds[49152 + wvOff]);
    gload16(bDc + 196608, &lds[49152 + 4096 + wvOff]);
    gload16(bDc + 393216, &lds[49152 + 8192 + wvOff]);
    __syncthreads();
    // ---- phase D: accO += u_cc @ W2slice ----
    int cd = 0;
    for (int kk = 0; kk < 4; ++kk) {
      if (kk < 3) {
        const u16* s = bDc + (kk + 1) * 32;
        int nb = 49152 + ((cd ^ 1) ? 12288 : 0);
        gload16(s,          &lds[nb + wvOff]);
        gload16(s + 196608, &lds[nb + 4096 + wvOff]);
        gload16(s + 393216, &lds[nb + 8192 + wvOff]);
      }
      bf16x8 au[4], bw[6];
      #pragma unroll
      for (int i = 0; i < 4; ++i) {
        int row = wr2 * 64 + i * 16 + l15;
        au[i] = *(const bf16x8*)&lds[row * 128 + ((((kk << 2) + l4) ^ l15) << 3)];
      }
      #pragma unroll
      for (int j = 0; j < 6; ++j)
        bw[j] = *(const bf16x8*)&lds[49152 + (cd ? 12288 : 0) + dbOff + j * 512];
      #pragma unroll
      for (int i = 0; i < 4; ++i)
        #pragma unroll
        for (int j = 0; j < 6; ++j)
          accO[i][j] = MFMA16(au[i], bw[j], accO[i][j]);
      __syncthreads();
      cd ^= 1;
    }
  }

  // epilogue: x += accO + b2
  #pragma unroll
  for (int i = 0; i < 4; ++i) {
    #pragma unroll
    for (int j = 0; j < 6; ++j) {
      int n = wc2 * 96 + j * 16 + l15;
      float bv = b2[n];
      #pragma unroll
      for (int r = 0; r < 4; ++r) {
        long row = mBase + wr2 * 64 + i * 16 + l4 * 4 + r;
        long idx = row * 384 + n;
        x[idx] = accO[i][j][r] + bv + x[idx];
      }
    }
  }
}

// ------------------------------------------------------------- head GEMM
template<int OBF>
__global__ __launch_bounds__(256) void gemm_head(const u16* __restrict__ A,
    const u16* __restrict__ Wt, const float* __restrict__ bias,
    void* __restrict__ outp, int N, int K)
{
  __shared__ __align__(16) u16 As[128][4][8];
  __shared__ __align__(16) u16 Bs[64][4][8];
  int tid  = threadIdx.x;
  int nt   = blockIdx.x;
  int nBase = nt * 64;
  long mBase = (long)blockIdx.y * 128;
  int lane = tid & 63, wv = tid >> 6;
  int l15 = lane & 15, l4 = lane >> 4;
  int sseg = tid & 3;
  int srow = tid >> 2;
  int swW = sseg ^ ((srow >> 2) & 3);
  int swR = l4 ^ (l15 >> 2);
  const u16* a0p = A + (mBase + srow) * K + sseg * 8;
  const u16* a1p = a0p + (long)64 * K;
  bool colOK = (nBase + srow) < N;
  const u16* bp  = Wt + (long)(nBase + srow) * K + sseg * 8;

  f32x4 acc[2][4];
  #pragma unroll
  for (int i = 0; i < 2; i++)
    #pragma unroll
    for (int j = 0; j < 4; j++)
      acc[i][j] = (f32x4){0.f, 0.f, 0.f, 0.f};

  for (int k0 = 0; k0 < K; k0 += 32) {
    uint4 av0 = *(const uint4*)(a0p + k0);
    uint4 av1 = *(const uint4*)(a1p + k0);
    uint4 bv  = colOK ? *(const uint4*)(bp + k0) : make_uint4(0, 0, 0, 0);
    *(uint4*)&As[srow][swW][0]      = av0;
    *(uint4*)&As[srow + 64][swW][0] = av1;
    *(uint4*)&Bs[srow][swW][0]      = bv;
    __syncthreads();
    bf16x8 af[2], bfr[4];
    af[0] = *(const bf16x8*)&As[wv * 32 + l15][swR][0];
    af[1] = *(const bf16x8*)&As[wv * 32 + 16 + l15][swR][0];
    #pragma unroll
    for (int j = 0; j < 4; j++)
      bfr[j] = *(const bf16x8*)&Bs[j * 16 + l15][swR][0];
    #pragma unroll
    for (int i = 0; i < 2; i++)
      #pragma unroll
      for (int j = 0; j < 4; j++)
        acc[i][j] = __builtin_amdgcn_mfma_f32_16x16x32_bf16(
            af[i], bfr[j], acc[i][j], 0, 0, 0);
    __syncthreads();
  }

  #pragma unroll
  for (int i = 0; i < 2; i++) {
    #pragma unroll
    for (int j = 0; j < 4; j++) {
      int n = nBase + j * 16 + l15;
      if (n < N) {
        #pragma unroll
        for (int r = 0; r < 4; r++) {
          long row = mBase + wv * 32 + i * 16 + l4 * 4 + r;
          float vv = acc[i][j][r];
          if (bias) vv += bias[n];
          if (OBF) ((u16*)outp)[row * N + n] = f2bf(vv);
          else     ((float*)outp)[row * N + n] = vv;
        }
      }
    }
  }
}

// ---------------------------------------------------------------- attention
// MFMA flash-style: one block per (b, head); qkv [BTc][1152]; ao [BTc][384].
__global__ __launch_bounds__(256) void attn_k(const u16* __restrict__ qkv,
    u16* __restrict__ ao)
{
  __shared__ __align__(16) u16 qs[64][72];
  __shared__ __align__(16) u16 ks[64][72];
  __shared__ __align__(16) u16 vT[64][72];
  __shared__ __align__(16) u16 ps[64][72];
  int tid = threadIdx.x;
  int bb = blockIdx.x / H_;
  int hh = blockIdx.x % H_;
  const u16* base = qkv + ((long)bb * T_) * 1152 + hh * HS_;

  for (int i = tid; i < 576; i += 256)
    ((uint4*)vT)[i] = make_uint4(0, 0, 0, 0);
  __syncthreads();

  for (int i = tid; i < 480; i += 256) {
    int t = i >> 3, d0 = (i & 7) << 3;
    const u16* rp = base + (long)t * 1152;
    *(uint4*)&qs[t][d0] = *(const uint4*)(rp + d0);
    *(uint4*)&ks[t][d0] = *(const uint4*)(rp + 384 + d0);
    uint4 rv = *(const uint4*)(rp + 768 + d0);
    u16 vv[8] = {(u16)(rv.x & 0xffffu), (u16)(rv.x >> 16),
                 (u16)(rv.y & 0xffffu), (u16)(rv.y >> 16),
                 (u16)(rv.z & 0xffffu), (u16)(rv.z >> 16),
                 (u16)(rv.w & 0xffffu), (u16)(rv.w >> 16)};
    #pragma unroll
    for (int m = 0; m < 8; m++) vT[d0 + m][t] = vv[m];
  }
  __syncthreads();

  int lane = tid & 63, wv = tid >> 6;
  int l15 = lane & 15, quad = lane >> 4;

  bf16x8 aq0 = *(const bf16x8*)&qs[wv * 16 + l15][quad * 8];
  bf16x8 aq1 = *(const bf16x8*)&qs[wv * 16 + l15][32 + quad * 8];
  f32x4 s[4];
  #pragma unroll
  for (int jt = 0; jt < 4; jt++) {
    bf16x8 b0 = *(const bf16x8*)&ks[jt * 16 + l15][quad * 8];
    bf16x8 b1 = *(const bf16x8*)&ks[jt * 16 + l15][32 + quad * 8];
    f32x4 a2 = (f32x4){0.f, 0.f, 0.f, 0.f};
    a2 = __builtin_amdgcn_mfma_f32_16x16x32_bf16(aq0, b0, a2, 0, 0, 0);
    a2 = __builtin_amdgcn_mfma_f32_16x16x32_bf16(aq1, b1, a2, 0, 0, 0);
    s[jt] = a2;
  }

  int rbase = wv * 16 + quad * 4;
  #pragma unroll
  for (int r = 0; r < 4; r++) {
    int row = rbase + r;
    float v0[4];
    #pragma unroll
    for (int jt = 0; jt < 4; jt++) {
      int col = jt * 16 + l15;
      float sv = s[jt][r] * 0.125f;
      v0[jt] = (col <= row) ? sv : -1e30f;
    }
    float m = fmaxf(fmaxf(v0[0], v0[1]), fmaxf(v0[2], v0[3]));
    #pragma unroll
    for (int off = 1; off < 16; off <<= 1) m = fmaxf(m, __shfl_xor(m, off, 64));
    float sum = 0.f;
    #pragma unroll
    for (int jt = 0; jt < 4; jt++) { v0[jt] = __expf(v0[jt] - m); sum += v0[jt]; }
    #pragma unroll
    for (int off = 1; off < 16; off <<= 1) sum += __shfl_xor(sum, off, 64);
    float inv = 1.f / sum;
    #pragma unroll
    for (int jt = 0; jt < 4; jt++)
      ps[row][jt * 16 + l15] = f2bf(v0[jt] * inv);
  }
  __syncthreads();

  bf16x8 ap0 = *(const bf16x8*)&ps[wv * 16 + l15][quad * 8];
  bf16x8 ap1 = *(const bf16x8*)&ps[wv * 16 + l15][32 + quad * 8];
  long obase = ((long)bb * T_) * C_ + hh * HS_;
  #pragma unroll
  for (int dt = 0; dt < 4; dt++) {
    bf16x8 b0 = *(const bf16x8*)&vT[dt * 16 + l15][quad * 8];
    bf16x8 b1 = *(const bf16x8*)&vT[dt * 16 + l15][32 + quad * 8];
    f32x4 a2 = (f32x4){0.f, 0.f, 0.f, 0.f};
    a2 = __builtin_amdgcn_mfma_f32_16x16x32_bf16(ap0, b0, a2, 0, 0, 0);
    a2 = __builtin_amdgcn_mfma_f32_16x16x32_bf16(ap1, b1, a2, 0, 0, 0);
    #pragma unroll
    for (int r = 0; r < 4; r++) {
      int row = rbase + r;
      if (row < T_)
        ao[obase + (long)row * C_ + dt * 16 + l15] = f2bf(a2[r]);
    }
  }
}

// ---------------------------------------------------------------- launch
extern "C" void kernel_launch(void* const* d_in, const int* in_sizes, int n_in,
                              void* d_out, int out_size, void* d_ws, size_t ws_size,
                              hipStream_t stream)
{
  const int*   ctx  = (const int*)  d_in[0];
  const float* tok  = (const float*)d_in[1];
  const float* pos  = (const float*)d_in[2];
  const float* wq   = (const float*)d_in[3];
  const float* wk   = (const float*)d_in[4];
  const float* wv   = (const float*)d_in[5];
  const float* wo   = (const float*)d_in[6];
  const float* bo   = (const float*)d_in[7];
  const float* ln1g = (const float*)d_in[8];
  const float* ln1b = (const float*)d_in[9];
  const float* ln2g = (const float*)d_in[10];
  const float* ln2b = (const float*)d_in[11];
  const float* w1   = (const float*)d_in[12];
  const float* b1   = (const float*)d_in[13];
  const float* w2   = (const float*)d_in[14];
  const float* b2   = (const float*)d_in[15];
  const float* lnfg = (const float*)d_in[16];
  const float* lnfb = (const float*)d_in[17];
  const float* lmw  = (const float*)d_in[18];
  const float* lmb  = (const float*)d_in[19];
  float* out = (float*)d_out;

  const long nQKV = (long)L_ * H_ * C_ * HS_;
  const long nWO  = (long)L_ * C_ * C_;
  const long nW1  = (long)L_ * C_ * FF_;
  const long nLM  = (long)C_ * V_;
  u16* wqkvT = (u16*)d_ws;                       // [L][1152][384]
  u16* woT = wqkvT + 3 * nQKV;
  u16* w1T = woT + nWO;
  u16* w2T = w1T + nW1;
  u16* lmT = w2T + nW1;
  const size_t wbytes = (size_t)(nQKV * 3 + nWO + nW1 * 2 + nLM) * 2;

  // 6U workspace: x(2U) + qkv(3U) + hab(1U); h aliases dead ab slot, fb gone.
  int chunkB = 32;
  {
    const int cand[] = {512, 256, 128, 64, 32};
    for (int i = 0; i < 5; i++) {
      size_t U = (size_t)cand[i] * T_ * C_ * 2;
      if (wbytes + 6 * U <= ws_size) { chunkB = cand[i]; break; }
    }
  }
  const long BTc = (long)chunkB * T_;
  char* wsb = (char*)d_ws + wbytes;
  const size_t U = (size_t)BTc * C_ * 2;
  float* x    = (float*)wsb;             // 2U
  u16*   qkvb = (u16*)(wsb + 2 * U);     // 3U
  u16*   hab  = (u16*)(wsb + 5 * U);     // 1U: h / ab (disjoint live ranges)

  {
    dim3 tb(32, 8);
    const long sL = 1152L * 384, sH = 64L * 384, sec = 384L * 384;
    tconv_k<<<dim3(2, 12, L_ * H_), tb, 0, stream>>>(wq, wqkvT,
        C_, HS_, (long)C_ * HS_, H_, sL, sH);
    tconv_k<<<dim3(2, 12, L_ * H_), tb, 0, stream>>>(wk, wqkvT + sec,
        C_, HS_, (long)C_ * HS_, H_, sL, sH);
    tconv_k<<<dim3(2, 12, L_ * H_), tb, 0, stream>>>(wv, wqkvT + 2 * sec,
        C_, HS_, (long)C_ * HS_, H_, sL, sH);
    tconv_k<<<dim3(12, 12, L_), tb, 0, stream>>>(wo, woT,
        C_, C_, (long)C_ * C_, 1, (long)C_ * C_, 0);
    tconv_k<<<dim3(48, 12, L_), tb, 0, stream>>>(w1, w1T,
        C_, FF_, (long)C_ * FF_, 1, (long)C_ * FF_, 0);
    tconv_k<<<dim3(12, 48, L_), tb, 0, stream>>>(w2, w2T,
        FF_, C_, (long)FF_ * C_, 1, (long)FF_ * C_, 0);
    tconv_k<<<dim3(3, 12, 1), tb, 0, stream>>>(lmw, lmT,
        C_, V_, (long)C_ * V_, 1, 0, 0);
  }

  const long qkvL = 1152L * 384;
  const long woL  = (long)C_ * C_;
  const long w1L  = (long)C_ * FF_;
  dim3 blk(256);
  dim3 blk5(512);
  dim3 gEmb((u32)(BTc * C_ / 4 / 256));
  dim3 gLN((u32)(BTc / 4));
  int mT = (int)(BTc / 128);
  dim3 gHd(2, (u32)(BTc / 128));
  dim3 gAt((u32)(chunkB * H_));

  for (int c0 = 0; c0 < B_; c0 += chunkB) {
    const long tok0 = (long)c0 * T_;
    const int* ctxc = ctx + tok0;
    float* outc = out + tok0 * V_;

    embed_k<<<gEmb, blk, 0, stream>>>(ctxc, tok, pos, x);

    for (int l = 0; l < L_; l++) {
      ln_k<<<gLN, blk, 0, stream>>>(x, ln1g + l * C_, ln1b + l * C_, hab);
      gemm128g<0,0,1><<<dim3(mT * 9), blk5, 0, stream>>>(hab, wqkvT + l * qkvL,
          nullptr, nullptr, qkvb, 1152, C_, mT, 9);
      attn_k<<<gAt, blk, 0, stream>>>(qkvb, hab);
      gemm128g<0,1,0><<<dim3(mT * 3), blk5, 0, stream>>>(hab, woT + l * woL,
          bo + l * C_, x, x, C_, C_, mT, 3);
      ln_k<<<gLN, blk, 0, stream>>>(x, ln2g + l * C_, ln2b + l * C_, hab);
      mlp_fused<<<dim3(mT), blk5, 0, stream>>>(hab, w1T + l * w1L,
          b1 + l * FF_, w2T + l * w1L, b2 + l * C_, x, mT);
    }

    ln_k<<<gLN, blk, 0, stream>>>(x, lnfg, lnfb, hab);
    gemm_head<0><<<gHd, blk, 0, stream>>>(hab, lmT, lmb, outc, V_, C_);
  }
}

// Round 12
// 5482.417 us; speedup vs baseline: 1.2315x; 1.0748x over previous
//
#include <hip/hip_runtime.h>

// ---------------------------------------------------------------------------
// SimpleGPT forward on MI355X. Round 20: R11 base + LN fused into the two
// residual GEMMs (wo, down; both N=384 = full row). R19 proved fusion deletes
// traffic but a 1-block/CU mega-kernel loses it back; LN-in-epilogue is the
// cheap fusion: the gemm already holds the full row + residual in regs.
// gemm_ln: 64x384 tile, 480 blocks (%8=0), 8 waves 2x4 (32x96/wave),
// R11 2-buffer gload_lds loop; epilogue: acc+=bias+x, 16-lane shfl row
// partials -> 2KB LDS cross-wave reduce -> write x (f32) + h=LN (bf16).
// Deletes 12 ln_k/chunk (x re-read 47MB each) + their launch bubbles.
// ---------------------------------------------------------------------------

#define B_  2048
#define T_  60
#define C_  384
#define H_  6
#define HS_ 64
#define L_  6
#define FF_ 1536
#define V_  65

typedef unsigned int  u32;
typedef unsigned short u16;
typedef short bf16x8 __attribute__((ext_vector_type(8)));
typedef float f32x4  __attribute__((ext_vector_type(4)));

__device__ __forceinline__ float bf2f(u32 u) {
  return __uint_as_float(u << 16);
}
__device__ __forceinline__ u16 f2bf(float f) {
  u32 u = __float_as_uint(f);
  u = u + 0x7FFFu + ((u >> 16) & 1u);   // RNE; inputs are finite
  return (u16)(u >> 16);
}

typedef const __attribute__((address_space(1))) unsigned int gas_u32;
typedef __attribute__((address_space(3))) unsigned int las_u32;
__device__ __forceinline__ void gload16(const u16* g, u16* l) {
  __builtin_amdgcn_global_load_lds((gas_u32*)g, (las_u32*)l, 16, 0, 0);
}
#define MFMA16(a, b, c) __builtin_amdgcn_mfma_f32_16x16x32_bf16((a), (b), (c), 0, 0, 0)

// ------------------------------------------------ weight transpose+convert
__global__ void tconv_k(const float* __restrict__ src, u16* __restrict__ dst,
                        int K, int N, long srcStride, int nH, long sL, long sH)
{
  __shared__ float t[32][33];
  int z = blockIdx.z;
  int l = z / nH, hh = z % nH;
  const float* s = src + (long)z * srcStride;
  u16* d = dst + l * sL + hh * sH;
  int n0 = blockIdx.x * 32, k0 = blockIdx.y * 32;
  for (int yy = threadIdx.y; yy < 32; yy += 8) {
    int k = k0 + yy, n = n0 + threadIdx.x;
    t[yy][threadIdx.x] = (k < K && n < N) ? s[(long)k * N + n] : 0.f;
  }
  __syncthreads();
  for (int yy = threadIdx.y; yy < 32; yy += 8) {
    int n = n0 + yy, k = k0 + threadIdx.x;
    if (n < N && k < K) d[(long)n * K + k] = f2bf(t[threadIdx.x][yy]);
  }
}

// ---------------------------------------------------------------- embedding
__global__ __launch_bounds__(256) void embed_k(const int* __restrict__ ctx,
    const float* __restrict__ tok, const float* __restrict__ pos,
    float* __restrict__ x)
{
  int idx = blockIdx.x * 256 + threadIdx.x;
  int row = idx / (C_ / 4);
  int c   = (idx % (C_ / 4)) * 4;
  int t   = row % T_;
  int tk  = ctx[row];
  float4 a = *(const float4*)(tok + (long)tk * C_ + c);
  float4 p = *(const float4*)(pos + (long)t  * C_ + c);
  float4 o = make_float4(a.x + p.x, a.y + p.y, a.z + p.z, a.w + p.w);
  *(float4*)(x + (long)idx * 4) = o;
}

// ---------------------------------------------------------------- layernorm
__global__ __launch_bounds__(256) void ln_k(const float* __restrict__ x,
    const float* __restrict__ g, const float* __restrict__ b,
    u16* __restrict__ h)
{
  int lane = threadIdx.x & 63;
  int wv   = threadIdx.x >> 6;
  long row = (long)blockIdx.x * 4 + wv;
  const float* xr = x + row * C_;
  int c0 = lane * 6;
  float v0[6];
  #pragma unroll
  for (int i = 0; i < 6; i++) v0[i] = xr[c0 + i];
  float s = 0.f, sq = 0.f;
  #pragma unroll
  for (int i = 0; i < 6; i++) { s += v0[i]; sq += v0[i] * v0[i]; }
  #pragma unroll
  for (int off = 32; off > 0; off >>= 1) {
    s  += __shfl_xor(s,  off, 64);
    sq += __shfl_xor(sq, off, 64);
  }
  float mu  = s * (1.f / C_);
  float var = sq * (1.f / C_) - mu * mu;
  float rs  = rsqrtf(var + 1e-5f);
  u16* hr = h + row * C_;
  #pragma unroll
  for (int i = 0; i < 6; i++) {
    float hv = (v0[i] - mu) * rs * g[c0 + i] + b[c0 + i];
    hr[c0 + i] = f2bf(hv);
  }
}

// ------------------------------------------------------------- MFMA GEMM 128
// R11 verbatim (qkv / mlp-up). out = act(A @ Wt^T + bias) [+resid].
template<int RELU, int RES, int OBF>
__global__ __launch_bounds__(512) void gemm128g(const u16* __restrict__ A,
    const u16* __restrict__ Wt, const float* __restrict__ bias,
    const float* __restrict__ resid, void* __restrict__ outp,
    int N, int K, int mT, int nT)
{
  __shared__ __align__(16) u16 As[2][128][4][8];   // 16 KB
  __shared__ __align__(16) u16 Bs[2][128][4][8];   // 16 KB
  int tid = threadIdx.x;
  int bid = blockIdx.x;
  int mtile, ntile;
  if ((mT & 7) == 0) {
    int xcd = bid & 7, loc = bid >> 3;
    int q = loc / nT;
    mtile = xcd * (mT >> 3) + q;
    ntile = loc - q * nT;
  } else {
    int q = bid / nT;
    mtile = q;
    ntile = bid - q * nT;
  }
  long mBase = (long)mtile * 128;
  int  nBase = ntile * 128;
  int lane = tid & 63, wv = tid >> 6;
  int l15 = lane & 15, l4 = lane >> 4;
  int wr = wv >> 1, wc = wv & 1;          // 4x2 wave grid, 32x64 per wave
  int srow = tid >> 2;
  int seg  = (tid & 3) ^ ((tid >> 4) & 3);
  const u16* aL = A  + (mBase + srow) * (long)K + seg * 8;
  const u16* bL = Wt + ((long)nBase + srow) * K + seg * 8;
  u16* aD0 = &As[0][wv << 4][0][0];       // wave-uniform LDS dests
  u16* bD0 = &Bs[0][wv << 4][0][0];
  u16* aD1 = &As[1][wv << 4][0][0];
  u16* bD1 = &Bs[1][wv << 4][0][0];
  int swR = l4 ^ (l15 >> 2);

  f32x4 acc[2][4];
  #pragma unroll
  for (int i = 0; i < 2; i++)
    #pragma unroll
    for (int j = 0; j < 4; j++)
      acc[i][j] = (f32x4){0.f, 0.f, 0.f, 0.f};

  gload16(aL, aD0);
  gload16(bL, bD0);
  __syncthreads();

  int cur = 0;
  for (int k0 = 0; k0 < K; k0 += 32) {
    if (k0 + 32 < K) {
      gload16(aL + k0 + 32, cur ? aD0 : aD1);
      gload16(bL + k0 + 32, cur ? bD0 : bD1);
    }
    bf16x8 af[2], bfr[4];
    #pragma unroll
    for (int i = 0; i < 2; i++)
      af[i] = *(const bf16x8*)&As[cur][wr * 32 + i * 16 + l15][swR][0];
    #pragma unroll
    for (int j = 0; j < 4; j++)
      bfr[j] = *(const bf16x8*)&Bs[cur][wc * 64 + j * 16 + l15][swR][0];
    #pragma unroll
    for (int i = 0; i < 2; i++)
      #pragma unroll
      for (int j = 0; j < 4; j++)
        acc[i][j] = __builtin_amdgcn_mfma_f32_16x16x32_bf16(
            af[i], bfr[j], acc[i][j], 0, 0, 0);
    __syncthreads();
    cur ^= 1;
  }

  #pragma unroll
  for (int i = 0; i < 2; i++) {
    #pragma unroll
    for (int j = 0; j < 4; j++) {
      int n = nBase + wc * 64 + j * 16 + l15;
      float bv = bias ? bias[n] : 0.f;
      #pragma unroll
      for (int r = 0; r < 4; r++) {
        long row = mBase + wr * 32 + i * 16 + l4 * 4 + r;
        float vv = acc[i][j][r] + bv;
        if (RELU) vv = fmaxf(vv, 0.f);
        if (RES)  vv += resid[row * N + n];
        if (OBF) ((u16*)outp)[row * N + n] = f2bf(vv);
        else     ((float*)outp)[row * N + n] = vv;
      }
    }
  }
}

// --------------------------------------------------------- GEMM + resid + LN
// x_new = A @ Wt^T + bias + x ; h = LN(x_new)*g + b. N = 384 (full row).
// 64x384 tile, 512 threads, 8 waves 2x4 (32x96/wave, acc 2x6).
// A-tile (64x32, 4KB): waves 0-3 stage 1 chunk/thread; B-tile (384x32, 24KB):
// all threads stage 3 chunks. Same source-side swizzle as gemm128g.
__global__ __launch_bounds__(512) void gemm_ln(const u16* __restrict__ A,
    const u16* __restrict__ Wt, const float* __restrict__ bias,
    const float* __restrict__ g, const float* __restrict__ b,
    float* __restrict__ x, u16* __restrict__ hout, int K, int mT)
{
  __shared__ __align__(16) u16 aBuf[2][2048];    // 8 KB
  __shared__ __align__(16) u16 bBuf[2][12288];   // 48 KB
  __shared__ float psum[64][4][2];               // 2 KB
  int tid = threadIdx.x;
  int bid = blockIdx.x;
  int mtile;
  if ((mT & 7) == 0) { int xcd = bid & 7; mtile = xcd * (mT >> 3) + (bid >> 3); }
  else mtile = bid;
  long mBase = (long)mtile * 64;
  int lane = tid & 63, w = tid >> 6;
  int l15 = lane & 15, l4 = lane >> 4;
  int wr = w >> 2, wc = w & 3;            // 2x4 wave grid, 32x96 per wave
  int srow = tid >> 2;                    // A rows 0..63 (tid<256); B +j*128
  int seg  = (tid & 3) ^ ((tid >> 4) & 3);
  const u16* aL = A  + (mBase + (srow & 63)) * (long)K + seg * 8;
  const u16* bL = Wt + (long)srow * K + seg * 8;
  int swR = l4 ^ (l15 >> 2);
  int aOff = (wr * 32 + l15) * 32 + swR * 8;
  int bOff = (wc * 96 + l15) * 32 + swR * 8;

  f32x4 acc[2][6];
  #pragma unroll
  for (int i = 0; i < 2; i++)
    #pragma unroll
    for (int j = 0; j < 6; j++)
      acc[i][j] = (f32x4){0.f, 0.f, 0.f, 0.f};

  // prologue: stage k=0
  if (w < 4) gload16(aL, &aBuf[0][w << 9]);
  #pragma unroll
  for (int j = 0; j < 3; j++)
    gload16(bL + (long)j * 128 * K, &bBuf[0][j * 4096 + (w << 9)]);
  __syncthreads();

  int cur = 0;
  for (int k0 = 0; k0 < K; k0 += 32) {
    if (k0 + 32 < K) {
      if (w < 4) gload16(aL + k0 + 32, &aBuf[cur ^ 1][w << 9]);
      #pragma unroll
      for (int j = 0; j < 3; j++)
        gload16(bL + (long)j * 128 * K + k0 + 32,
                &bBuf[cur ^ 1][j * 4096 + (w << 9)]);
    }
    bf16x8 af[2], bf[6];
    #pragma unroll
    for (int i = 0; i < 2; i++)
      af[i] = *(const bf16x8*)&aBuf[cur][aOff + i * 512];
    #pragma unroll
    for (int j = 0; j < 6; j++)
      bf[j] = *(const bf16x8*)&bBuf[cur][bOff + j * 512];
    #pragma unroll
    for (int i = 0; i < 2; i++)
      #pragma unroll
      for (int j = 0; j < 6; j++)
        acc[i][j] = MFMA16(af[i], bf[j], acc[i][j]);
    __syncthreads();
    cur ^= 1;
  }

  // epilogue: acc += bias + resid(x); row partials; cross-wave LN
  #pragma unroll
  for (int j = 0; j < 6; j++) {
    int n = wc * 96 + j * 16 + l15;
    float bv = bias[n];
    #pragma unroll
    for (int i = 0; i < 2; i++)
      #pragma unroll
      for (int r = 0; r < 4; r++) {
        long rowg = mBase + wr * 32 + i * 16 + l4 * 4 + r;
        acc[i][j][r] += bv + x[rowg * 384 + n];
      }
  }
  #pragma unroll
  for (int i = 0; i < 2; i++)
    #pragma unroll
    for (int r = 0; r < 4; r++) {
      float s = 0.f, sq = 0.f;
      #pragma unroll
      for (int j = 0; j < 6; j++) {
        float vv = acc[i][j][r];
        s += vv; sq += vv * vv;
      }
      #pragma unroll
      for (int off = 1; off < 16; off <<= 1) {
        s  += __shfl_xor(s,  off, 64);
        sq += __shfl_xor(sq, off, 64);
      }
      if (l15 == 0) {
        int row = wr * 32 + i * 16 + l4 * 4 + r;
        psum[row][wc][0] = s;
        psum[row][wc][1] = sq;
      }
    }
  __syncthreads();
  #pragma unroll
  for (int i = 0; i < 2; i++)
    #pragma unroll
    for (int r = 0; r < 4; r++) {
      int row = wr * 32 + i * 16 + l4 * 4 + r;
      float s  = psum[row][0][0] + psum[row][1][0] + psum[row][2][0] + psum[row][3][0];
      float sq = psum[row][0][1] + psum[row][1][1] + psum[row][2][1] + psum[row][3][1];
      float mu  = s * (1.f / 384.f);
      float var = sq * (1.f / 384.f) - mu * mu;
      float rs  = rsqrtf(var + 1e-5f);
      long rowg = mBase + row;
      #pragma unroll
      for (int j = 0; j < 6; j++) {
        int n = wc * 96 + j * 16 + l15;
        float vv = acc[i][j][r];
        x[rowg * 384 + n] = vv;
        hout[rowg * 384 + n] = f2bf((vv - mu) * rs * g[n] + b[n]);
      }
    }
}

// ------------------------------------------------------------- head GEMM
template<int OBF>
__global__ __launch_bounds__(256) void gemm_head(const u16* __restrict__ A,
    const u16* __restrict__ Wt, const float* __restrict__ bias,
    void* __restrict__ outp, int N, int K)
{
  __shared__ __align__(16) u16 As[128][4][8];
  __shared__ __align__(16) u16 Bs[64][4][8];
  int tid  = threadIdx.x;
  int nt   = blockIdx.x;
  int nBase = nt * 64;
  long mBase = (long)blockIdx.y * 128;
  int lane = tid & 63, wv = tid >> 6;
  int l15 = lane & 15, l4 = lane >> 4;
  int sseg = tid & 3;
  int srow = tid >> 2;
  int swW = sseg ^ ((srow >> 2) & 3);
  int swR = l4 ^ (l15 >> 2);
  const u16* a0p = A + (mBase + srow) * K + sseg * 8;
  const u16* a1p = a0p + (long)64 * K;
  bool colOK = (nBase + srow) < N;
  const u16* bp  = Wt + (long)(nBase + srow) * K + sseg * 8;

  f32x4 acc[2][4];
  #pragma unroll
  for (int i = 0; i < 2; i++)
    #pragma unroll
    for (int j = 0; j < 4; j++)
      acc[i][j] = (f32x4){0.f, 0.f, 0.f, 0.f};

  for (int k0 = 0; k0 < K; k0 += 32) {
    uint4 av0 = *(const uint4*)(a0p + k0);
    uint4 av1 = *(const uint4*)(a1p + k0);
    uint4 bv  = colOK ? *(const uint4*)(bp + k0) : make_uint4(0, 0, 0, 0);
    *(uint4*)&As[srow][swW][0]      = av0;
    *(uint4*)&As[srow + 64][swW][0] = av1;
    *(uint4*)&Bs[srow][swW][0]      = bv;
    __syncthreads();
    bf16x8 af[2], bfr[4];
    af[0] = *(const bf16x8*)&As[wv * 32 + l15][swR][0];
    af[1] = *(const bf16x8*)&As[wv * 32 + 16 + l15][swR][0];
    #pragma unroll
    for (int j = 0; j < 4; j++)
      bfr[j] = *(const bf16x8*)&Bs[j * 16 + l15][swR][0];
    #pragma unroll
    for (int i = 0; i < 2; i++)
      #pragma unroll
      for (int j = 0; j < 4; j++)
        acc[i][j] = __builtin_amdgcn_mfma_f32_16x16x32_bf16(
            af[i], bfr[j], acc[i][j], 0, 0, 0);
    __syncthreads();
  }

  #pragma unroll
  for (int i = 0; i < 2; i++) {
    #pragma unroll
    for (int j = 0; j < 4; j++) {
      int n = nBase + j * 16 + l15;
      if (n < N) {
        #pragma unroll
        for (int r = 0; r < 4; r++) {
          long row = mBase + wv * 32 + i * 16 + l4 * 4 + r;
          float vv = acc[i][j][r];
          if (bias) vv += bias[n];
          if (OBF) ((u16*)outp)[row * N + n] = f2bf(vv);
          else     ((float*)outp)[row * N + n] = vv;
        }
      }
    }
  }
}

// ---------------------------------------------------------------- attention
// MFMA flash-style: one block per (b, head); qkv [BTc][1152]; ao [BTc][384].
__global__ __launch_bounds__(256) void attn_k(const u16* __restrict__ qkv,
    u16* __restrict__ ao)
{
  __shared__ __align__(16) u16 qs[64][72];
  __shared__ __align__(16) u16 ks[64][72];
  __shared__ __align__(16) u16 vT[64][72];
  __shared__ __align__(16) u16 ps[64][72];
  int tid = threadIdx.x;
  int bb = blockIdx.x / H_;
  int hh = blockIdx.x % H_;
  const u16* base = qkv + ((long)bb * T_) * 1152 + hh * HS_;

  for (int i = tid; i < 576; i += 256)
    ((uint4*)vT)[i] = make_uint4(0, 0, 0, 0);
  __syncthreads();

  for (int i = tid; i < 480; i += 256) {
    int t = i >> 3, d0 = (i & 7) << 3;
    const u16* rp = base + (long)t * 1152;
    *(uint4*)&qs[t][d0] = *(const uint4*)(rp + d0);
    *(uint4*)&ks[t][d0] = *(const uint4*)(rp + 384 + d0);
    uint4 rv = *(const uint4*)(rp + 768 + d0);
    u16 vv[8] = {(u16)(rv.x & 0xffffu), (u16)(rv.x >> 16),
                 (u16)(rv.y & 0xffffu), (u16)(rv.y >> 16),
                 (u16)(rv.z & 0xffffu), (u16)(rv.z >> 16),
                 (u16)(rv.w & 0xffffu), (u16)(rv.w >> 16)};
    #pragma unroll
    for (int m = 0; m < 8; m++) vT[d0 + m][t] = vv[m];
  }
  __syncthreads();

  int lane = tid & 63, wv = tid >> 6;
  int l15 = lane & 15, quad = lane >> 4;

  bf16x8 aq0 = *(const bf16x8*)&qs[wv * 16 + l15][quad * 8];
  bf16x8 aq1 = *(const bf16x8*)&qs[wv * 16 + l15][32 + quad * 8];
  f32x4 s[4];
  #pragma unroll
  for (int jt = 0; jt < 4; jt++) {
    bf16x8 b0 = *(const bf16x8*)&ks[jt * 16 + l15][quad * 8];
    bf16x8 b1 = *(const bf16x8*)&ks[jt * 16 + l15][32 + quad * 8];
    f32x4 a2 = (f32x4){0.f, 0.f, 0.f, 0.f};
    a2 = __builtin_amdgcn_mfma_f32_16x16x32_bf16(aq0, b0, a2, 0, 0, 0);
    a2 = __builtin_amdgcn_mfma_f32_16x16x32_bf16(aq1, b1, a2, 0, 0, 0);
    s[jt] = a2;
  }

  int rbase = wv * 16 + quad * 4;
  #pragma unroll
  for (int r = 0; r < 4; r++) {
    int row = rbase + r;
    float v0[4];
    #pragma unroll
    for (int jt = 0; jt < 4; jt++) {
      int col = jt * 16 + l15;
      float sv = s[jt][r] * 0.125f;
      v0[jt] = (col <= row) ? sv : -1e30f;
    }
    float m = fmaxf(fmaxf(v0[0], v0[1]), fmaxf(v0[2], v0[3]));
    #pragma unroll
    for (int off = 1; off < 16; off <<= 1) m = fmaxf(m, __shfl_xor(m, off, 64));
    float sum = 0.f;
    #pragma unroll
    for (int jt = 0; jt < 4; jt++) { v0[jt] = __expf(v0[jt] - m); sum += v0[jt]; }
    #pragma unroll
    for (int off = 1; off < 16; off <<= 1) sum += __shfl_xor(sum, off, 64);
    float inv = 1.f / sum;
    #pragma unroll
    for (int jt = 0; jt < 4; jt++)
      ps[row][jt * 16 + l15] = f2bf(v0[jt] * inv);
  }
  __syncthreads();

  bf16x8 ap0 = *(const bf16x8*)&ps[wv * 16 + l15][quad * 8];
  bf16x8 ap1 = *(const bf16x8*)&ps[wv * 16 + l15][32 + quad * 8];
  long obase = ((long)bb * T_) * C_ + hh * HS_;
  #pragma unroll
  for (int dt = 0; dt < 4; dt++) {
    bf16x8 b0 = *(const bf16x8*)&vT[dt * 16 + l15][quad * 8];
    bf16x8 b1 = *(const bf16x8*)&vT[dt * 16 + l15][32 + quad * 8];
    f32x4 a2 = (f32x4){0.f, 0.f, 0.f, 0.f};
    a2 = __builtin_amdgcn_mfma_f32_16x16x32_bf16(ap0, b0, a2, 0, 0, 0);
    a2 = __builtin_amdgcn_mfma_f32_16x16x32_bf16(ap1, b1, a2, 0, 0, 0);
    #pragma unroll
    for (int r = 0; r < 4; r++) {
      int row = rbase + r;
      if (row < T_)
        ao[obase + (long)row * C_ + dt * 16 + l15] = f2bf(a2[r]);
    }
  }
}

// ---------------------------------------------------------------- launch
extern "C" void kernel_launch(void* const* d_in, const int* in_sizes, int n_in,
                              void* d_out, int out_size, void* d_ws, size_t ws_size,
                              hipStream_t stream)
{
  const int*   ctx  = (const int*)  d_in[0];
  const float* tok  = (const float*)d_in[1];
  const float* pos  = (const float*)d_in[2];
  const float* wq   = (const float*)d_in[3];
  const float* wk   = (const float*)d_in[4];
  const float* wv   = (const float*)d_in[5];
  const float* wo   = (const float*)d_in[6];
  const float* bo   = (const float*)d_in[7];
  const float* ln1g = (const float*)d_in[8];
  const float* ln1b = (const float*)d_in[9];
  const float* ln2g = (const float*)d_in[10];
  const float* ln2b = (const float*)d_in[11];
  const float* w1   = (const float*)d_in[12];
  const float* b1   = (const float*)d_in[13];
  const float* w2   = (const float*)d_in[14];
  const float* b2   = (const float*)d_in[15];
  const float* lnfg = (const float*)d_in[16];
  const float* lnfb = (const float*)d_in[17];
  const float* lmw  = (const float*)d_in[18];
  const float* lmb  = (const float*)d_in[19];
  float* out = (float*)d_out;

  const long nQKV = (long)L_ * H_ * C_ * HS_;
  const long nWO  = (long)L_ * C_ * C_;
  const long nW1  = (long)L_ * C_ * FF_;
  const long nLM  = (long)C_ * V_;
  u16* wqkvT = (u16*)d_ws;                       // [L][1152][384]
  u16* woT = wqkvT + 3 * nQKV;
  u16* w1T = woT + nWO;
  u16* w2T = w1T + nW1;
  u16* lmT = w2T + nW1;
  const size_t wbytes = (size_t)(nQKV * 3 + nWO + nW1 * 2 + nLM) * 2;

  int chunkB = 32;
  {
    const int cand[] = {2048, 1024, 512, 256, 128, 64, 32};
    for (int i = 0; i < 7; i++) {
      size_t U = (size_t)cand[i] * T_ * C_ * 2;
      if (wbytes + 7 * U <= ws_size) { chunkB = cand[i]; break; }
    }
  }
  const long BTc = (long)chunkB * T_;
  char* wsb = (char*)d_ws + wbytes;
  const size_t U = (size_t)BTc * C_ * 2;
  float* x    = (float*)wsb;             // 2U
  u16*   hab  = (u16*)(wsb + 2 * U);     // 1U: h / ab (disjoint live ranges)
  char*  reg  = wsb + 3 * U;             // 4U: qkv(3U); fb(4U) aliases
  u16* qkvb = (u16*)reg;
  u16* fb   = (u16*)reg;                 // qkv dead before MLP-up output

  {
    dim3 tb(32, 8);
    const long sL = 1152L * 384, sH = 64L * 384, sec = 384L * 384;
    tconv_k<<<dim3(2, 12, L_ * H_), tb, 0, stream>>>(wq, wqkvT,
        C_, HS_, (long)C_ * HS_, H_, sL, sH);
    tconv_k<<<dim3(2, 12, L_ * H_), tb, 0, stream>>>(wk, wqkvT + sec,
        C_, HS_, (long)C_ * HS_, H_, sL, sH);
    tconv_k<<<dim3(2, 12, L_ * H_), tb, 0, stream>>>(wv, wqkvT + 2 * sec,
        C_, HS_, (long)C_ * HS_, H_, sL, sH);
    tconv_k<<<dim3(12, 12, L_), tb, 0, stream>>>(wo, woT,
        C_, C_, (long)C_ * C_, 1, (long)C_ * C_, 0);
    tconv_k<<<dim3(48, 12, L_), tb, 0, stream>>>(w1, w1T,
        C_, FF_, (long)C_ * FF_, 1, (long)C_ * FF_, 0);
    tconv_k<<<dim3(12, 48, L_), tb, 0, stream>>>(w2, w2T,
        FF_, C_, (long)FF_ * C_, 1, (long)FF_ * C_, 0);
    tconv_k<<<dim3(3, 12, 1), tb, 0, stream>>>(lmw, lmT,
        C_, V_, (long)C_ * V_, 1, 0, 0);
  }

  const long qkvL = 1152L * 384;
  const long woL  = (long)C_ * C_;
  const long w1L  = (long)C_ * FF_;
  dim3 blk(256);
  dim3 blk5(512);
  dim3 gEmb((u32)(BTc * C_ / 4 / 256));
  dim3 gLN((u32)(BTc / 4));
  int mT   = (int)(BTc / 128);
  int mT64 = (int)(BTc / 64);
  dim3 gHd(2, (u32)(BTc / 128));
  dim3 gAt((u32)(chunkB * H_));

  for (int c0 = 0; c0 < B_; c0 += chunkB) {
    const long tok0 = (long)c0 * T_;
    const int* ctxc = ctx + tok0;
    float* outc = out + tok0 * V_;

    embed_k<<<gEmb, blk, 0, stream>>>(ctxc, tok, pos, x);
    ln_k<<<gLN, blk, 0, stream>>>(x, ln1g, ln1b, hab);   // ln1 layer 0

    for (int l = 0; l < L_; l++) {
      gemm128g<0,0,1><<<dim3(mT * 9), blk5, 0, stream>>>(hab, wqkvT + l * qkvL,
          nullptr, nullptr, qkvb, 1152, C_, mT, 9);
      attn_k<<<gAt, blk, 0, stream>>>(qkvb, hab);
      // wo + resid + ln2 fused
      gemm_ln<<<dim3(mT64), blk5, 0, stream>>>(hab, woT + l * woL,
          bo + l * C_, ln2g + l * C_, ln2b + l * C_, x, hab, C_, mT64);
      gemm128g<1,0,1><<<dim3(mT * 12), blk5, 0, stream>>>(hab, w1T + l * w1L,
          b1 + l * FF_, nullptr, fb, FF_, C_, mT, 12);
      // down + resid + (ln1 of l+1 | lnf) fused
      const float* gg = (l < L_ - 1) ? (ln1g + (l + 1) * C_) : lnfg;
      const float* bb = (l < L_ - 1) ? (ln1b + (l + 1) * C_) : lnfb;
      gemm_ln<<<dim3(mT64), blk5, 0, stream>>>(fb, w2T + l * w1L,
          b2 + l * C_, gg, bb, x, hab, FF_, mT64);
    }

    gemm_head<0><<<gHd, blk, 0, stream>>>(hab, lmT, lmb, outc, V_, C_);
  }
}